// Round 9
// baseline (216.376 us; speedup 1.0000x reference)
//
#include <hip/hip_runtime.h>

typedef unsigned short u16;
typedef unsigned int u32;

#define CH 128      // IN_CH == HEADS*HEAD_DIM == 128
#define NHEAD 4
#define NEG_SLOPE 0.2f
#define ROWS_PER_BLOCK 32   // x-tile rows per block

#define LOG_NPB 7
#define NPB 128             // nodes per coarse bucket (bucket = dst >> 7)
#define NBMAX 400           // LDS bound on bucket count (N <= 51200)
#define BCAP 6144           // records per bucket (E[edges]=4096, ~32 sigma)
#define HCAP 4096           // records per HALF-bucket in binBagg (mean 2048)
#define KMB 12              // BCAP / 512 records per thread in binBagg
#define GPAD 16             // bucket-cursor padding (one per 64B line)
#define BINA_BLOCKS 256     // global atomics = BINA_BLOCKS * NB ~ 100k

static __device__ __forceinline__ float bitf(u32 i) {
    float f; __builtin_memcpy(&f, &i, 4); return f;
}
static __device__ __forceinline__ float bflo(u32 v) { return bitf(v << 16); }
static __device__ __forceinline__ float bfhi(u32 v) { return bitf(v & 0xffff0000u); }
static __device__ __forceinline__ u16 f2bf(float f) {
    u32 i; __builtin_memcpy(&i, &f, 4);
    return (u16)((i + 0x7fffu + ((i >> 16) & 1u)) >> 16);   // RNE
}
static __device__ __forceinline__ float lrelu(float v) { return v > 0.f ? v : NEG_SLOPE * v; }

// edge_index accessor: mode32 ? int32 layout : int64 layout (low word)
static __device__ __forceinline__ int ei_at(const int* __restrict__ ei, int mode32, size_t idx) {
    return mode32 ? ei[idx] : ei[2 * idx];
}

// ---------------- k0: init — zero gcur + convert W to bf16 pairs (global) ----------------
// Replaces the hipMemsetAsync dispatch; W converted ONCE instead of per-GEMM-block.
// Wg linear layout == Wbf[row][c2] row-major: for float4 index t, pair indices are 2t, 2t+1.
__global__ __launch_bounds__(256) void init_kernel(
    const float* __restrict__ W, u32* __restrict__ Wg, int* __restrict__ gcur, int nGcur)
{
    const int t = blockIdx.x * 256 + threadIdx.x;    // grid 16x256 = 4096 float4s
    float4 w4 = ((const float4*)W)[t];
    Wg[2 * t]     = (u32)f2bf(w4.x) | ((u32)f2bf(w4.y) << 16);
    Wg[2 * t + 1] = (u32)f2bf(w4.z) | ((u32)f2bf(w4.w) << 16);
    for (int i = t; i < nGcur; i += 4096) gcur[i] = 0;
}

// ======== k1: blocks [0,BINA_BLOCKS) do binA, rest do GEMM (r3-proven form) ========
// LDS: xs (16 KB) overlaid with binA's hist arrays; Wbf staged from pre-converted
// Wg (8 uint4 loads/thread, zero conversion VALU). Total LDS 48 KB -> 3 blocks/CU.
__global__ __launch_bounds__(256) void gemmbin_kernel(
    const float* __restrict__ x, const u32* __restrict__ Wg,
    const float* __restrict__ att_src, const float* __restrict__ att_dst,
    u16* __restrict__ h, float* __restrict__ asrc, float* __restrict__ adst, int N,
    const int* __restrict__ ei, int* __restrict__ gcur, u32* __restrict__ rec,
    int E, int NB)
{
    __shared__ float xs[ROWS_PER_BLOCK][CH];   // 16 KB (overlaid by binA state)
    __shared__ u32 Wbf[CH][CH / 2];            // 32 KB (bf16 pairs)

    const int tid = threadIdx.x;

    if (blockIdx.x < BINA_BLOCKS) {
        // ---- binA: partition edges into coarse buckets ----
        int* hist  = (int*)&xs[0][0];          // 3 * NBMAX ints = 4.8 KB <= 16 KB
        int* hbase = hist + NBMAX;
        int* hcur  = hbase + NBMAX;
        // inline dtype probe: int64 data has all odd words == 0
        const int mode32 = __syncthreads_or(ei[2 * tid + 1] != 0);
        for (int b = tid; b < NB; b += 256) { hist[b] = 0; hcur[b] = 0; }
        __syncthreads();
        const int chunk = (E + BINA_BLOCKS - 1) / BINA_BLOCKS;
        const int beg0 = blockIdx.x * chunk;
        const int end0 = min(E, beg0 + chunk);
#pragma unroll 4
        for (int e = beg0 + tid; e < end0; e += 256) {
            int dj = ei_at(ei, mode32, (size_t)E + e);
            atomicAdd(&hist[dj >> LOG_NPB], 1);
        }
        __syncthreads();
        for (int b = tid; b < NB; b += 256) {
            int c = hist[b];
            hbase[b] = c ? atomicAdd(&gcur[b * GPAD], c) : 0;
        }
        __syncthreads();
#pragma unroll 4
        for (int e = beg0 + tid; e < end0; e += 256) {
            int dj = ei_at(ei, mode32, (size_t)E + e);
            int sj = ei_at(ei, mode32, (size_t)e);
            int bkt = dj >> LOG_NPB;
            int r = atomicAdd(&hcur[bkt], 1);
            int pos = hbase[bkt] + r;
            if (pos < BCAP)
                rec[(size_t)bkt * BCAP + pos] = ((u32)sj << LOG_NPB) | (u32)(dj & (NPB - 1));
        }
        return;
    }

    // ---- GEMM h = x@W + logits ----
    const int gb = blockIdx.x - BINA_BLOCKS;
    const int r0b = gb * ROWS_PER_BLOCK;
    {
        const uint4* Wg4 = (const uint4*)Wg;
        uint4* Wb4 = (uint4*)&Wbf[0][0];
#pragma unroll
        for (int i = 0; i < 8; ++i) {           // stage pre-converted Wbf (32 KB)
            int f = tid + i * 256;              // 2048 uint4s
            Wb4[f] = Wg4[f];
        }
#pragma unroll
        for (int i = 0; i < 4; ++i) {           // stage x tile fp32
            int f = tid + i * 256;
            int row = f >> 5;
            int col = (f & 31) * 4;
            if (r0b + row < N)
                *(float4*)&xs[row][col] = *(const float4*)(x + (size_t)(r0b + row) * CH + col);
        }
    }
    __syncthreads();

    const int lane = tid & 63;
    const int wave = tid >> 6;
    const int c0 = lane * 2;
    const int head = lane >> 4;
    const float as0 = att_src[c0], as1 = att_src[c0 + 1];
    const float ad0 = att_dst[c0], ad1 = att_dst[c0 + 1];
    const int rw = wave * 8;

    float acc[8][2];
#pragma unroll
    for (int r = 0; r < 8; ++r) { acc[r][0] = 0.f; acc[r][1] = 0.f; }

#pragma unroll 4
    for (int k4 = 0; k4 < 32; ++k4) {
        const int k = k4 * 4;
        u32 p0 = Wbf[k + 0][lane];   // word index k*64+lane -> bank lane%32: 2-way, free
        u32 p1 = Wbf[k + 1][lane];
        u32 p2 = Wbf[k + 2][lane];
        u32 p3 = Wbf[k + 3][lane];
        float w00 = bflo(p0), w01 = bfhi(p0);
        float w10 = bflo(p1), w11 = bfhi(p1);
        float w20 = bflo(p2), w21 = bfhi(p2);
        float w30 = bflo(p3), w31 = bfhi(p3);
#pragma unroll
        for (int r = 0; r < 8; ++r) {
            float4 xv = *(const float4*)&xs[rw + r][k];   // wave-uniform LDS broadcast
            acc[r][0] = fmaf(xv.x, w00, acc[r][0]);
            acc[r][1] = fmaf(xv.x, w01, acc[r][1]);
            acc[r][0] = fmaf(xv.y, w10, acc[r][0]);
            acc[r][1] = fmaf(xv.y, w11, acc[r][1]);
            acc[r][0] = fmaf(xv.z, w20, acc[r][0]);
            acc[r][1] = fmaf(xv.z, w21, acc[r][1]);
            acc[r][0] = fmaf(xv.w, w30, acc[r][0]);
            acc[r][1] = fmaf(xv.w, w31, acc[r][1]);
        }
    }
#pragma unroll
    for (int r = 0; r < 8; ++r) {
        int row = r0b + rw + r;
        float sdot = acc[r][0] * as0 + acc[r][1] * as1;
        float ddot = acc[r][0] * ad0 + acc[r][1] * ad1;
#pragma unroll
        for (int o = 1; o < 16; o <<= 1) {
            sdot += __shfl_xor(sdot, o, 64);
            ddot += __shfl_xor(ddot, o, 64);
        }
        if (row < N) {
            u32 hp = (u32)f2bf(acc[r][0]) | ((u32)f2bf(acc[r][1]) << 16);
            *(u32*)(h + (size_t)row * CH + c0) = hp;
            if ((lane & 15) == 0) {
                asrc[row * NHEAD + head] = sdot;
                adst[row * NHEAD + head] = ddot;
            }
        }
    }
}

// ======== k2: fused binB + aggregate — one block per HALF-bucket, 512 threads ========
// 2*NB = 782 blocks -> ~3 blocks/CU (24 waves, 75%) vs r8's 1.5 blocks/CU (51%).
// Each block reads the whole bucket's records, keeps its half (64 nodes), builds
// the CSR in LDS, then 8 waves x 8 nodes aggregate (proven inner loop).
__global__ __launch_bounds__(512) void binBagg_kernel(
    const u16* __restrict__ h, const float* __restrict__ asrc, const float* __restrict__ adst,
    const int* __restrict__ gcur, const u32* __restrict__ rec,
    const float* __restrict__ bias, float* __restrict__ out, int N)
{
    __shared__ int outb[HCAP + 32];   // 16.5 KB (+pad for prefetch overread)
    __shared__ int lcnt[64];
    __shared__ int lsc[64];
    __shared__ int lcur[64];
    const int tid = threadIdx.x;
    const int bkt  = blockIdx.x >> 1;
    const int half = blockIdx.x & 1;
    int cnt0 = gcur[bkt * GPAD];
    cnt0 = cnt0 < BCAP ? cnt0 : BCAP;
    const size_t rbase = (size_t)bkt * BCAP;

    if (tid < 64) { lcnt[tid] = 0; lcur[tid] = 0; }

    u32 rc[KMB];
#pragma unroll
    for (int k = 0; k < KMB; ++k) {
        int i = tid + k * 512;
        rc[k] = (i < cnt0) ? rec[rbase + i] : 0xffffffffu;   // sj<<7|d < 6.5M, sentinel safe
    }
    __syncthreads();
#pragma unroll
    for (int k = 0; k < KMB; ++k) {
        u32 r = rc[k];
        if (r != 0xffffffffu && (int)((r & 127) >> 6) == half)
            atomicAdd(&lcnt[r & 63], 1);
    }
    __syncthreads();
    if (tid < 64) lsc[tid] = lcnt[tid];
    __syncthreads();
    for (int o = 1; o < 64; o <<= 1) {
        int v = (tid < 64 && tid >= o) ? lsc[tid - o] : 0;
        __syncthreads();
        if (tid < 64) lsc[tid] += v;
        __syncthreads();
    }
#pragma unroll
    for (int k = 0; k < KMB; ++k) {
        u32 r = rc[k];
        if (r != 0xffffffffu && (int)((r & 127) >> 6) == half) {
            int local = r & 63;
            int rr = atomicAdd(&lcur[local], 1);
            int slot = (lsc[local] - lcnt[local]) + rr;
            if (slot < HCAP) outb[slot] = (int)(r >> LOG_NPB);
        }
    }
    __syncthreads();

    // ---- agg phase: wave w handles locals w*8 .. w*8+7 (no barriers below) ----
    const int lane = tid & 63;
    const int wave = tid >> 6;        // 0..7
    const int g = lane >> 4;
    const int l = lane & 15;
    const int c8 = l * 8;
    const int head = l >> 2;

    for (int nl = 0; nl < 8; ++nl) {
        const int local = wave * 8 + nl;
        const int node = (bkt << LOG_NPB) + half * 64 + local;
        if (node >= N) continue;      // wave-uniform branch
        int end = lsc[local];
        const int beg = end - lcnt[local];
        end = end < HCAP ? end : HCAP;
        const float4 ad4 = *(const float4*)(adst + node * 4);
        const float adh = (head == 0) ? ad4.x : (head == 1) ? ad4.y : (head == 2) ? ad4.z : ad4.w;
        const float4 asl = *(const float4*)(asrc + node * 4);
        const float aslh = (head == 0) ? asl.x : (head == 1) ? asl.y : (head == 2) ? asl.z : asl.w;
        const float mh = lrelu(aslh + adh);   // self-loop logit as softmax shift

        float acc[8];
#pragma unroll
        for (int k = 0; k < 8; ++k) acc[k] = 0.f;
        float s = 0.f;

        int e = beg + g;
        if (e < end) {
            uint4 hC[4]; float aC[4];
#pragma unroll
            for (int i = 0; i < 4; ++i) {              // prologue batch: e+0,4,8,12
                int ei = e + 4 * i;
                int j = outb[ei];                      // LDS, padded-safe
                j = ((u32)j < (u32)N) ? j : 0;
                float a = asrc[j * NHEAD + head];
                aC[i] = (ei < end) ? a : -1e30f;
                hC[i] = *(const uint4*)(h + (size_t)j * CH + c8);
            }
            for (;;) {
                const int ebase = e + 16;
                uint4 hP[4]; float aP[4];
#pragma unroll
                for (int i = 0; i < 4; ++i) {          // prefetch next batch
                    int ei = ebase + 4 * i;
                    int j = outb[ei];                  // LDS, padded-safe
                    j = ((u32)j < (u32)N) ? j : 0;
                    float a = asrc[j * NHEAD + head];
                    aP[i] = (ei < end) ? a : -1e30f;
                    hP[i] = *(const uint4*)(h + (size_t)j * CH + c8);
                }
#pragma unroll
                for (int i = 0; i < 4; ++i) {          // compute current batch
                    float w = __expf(lrelu(aC[i] + adh) - mh);   // a=-1e30 -> w=0
                    s += w;
                    acc[0] = fmaf(w, bflo(hC[i].x), acc[0]);
                    acc[1] = fmaf(w, bfhi(hC[i].x), acc[1]);
                    acc[2] = fmaf(w, bflo(hC[i].y), acc[2]);
                    acc[3] = fmaf(w, bfhi(hC[i].y), acc[3]);
                    acc[4] = fmaf(w, bflo(hC[i].z), acc[4]);
                    acc[5] = fmaf(w, bfhi(hC[i].z), acc[5]);
                    acc[6] = fmaf(w, bflo(hC[i].w), acc[6]);
                    acc[7] = fmaf(w, bfhi(hC[i].w), acc[7]);
                }
#pragma unroll
                for (int i = 0; i < 4; ++i) { aC[i] = aP[i]; hC[i] = hP[i]; }
                e = ebase;
                if (e >= end) break;
            }
        }
        if (g == 0) {   // self-loop message: w = exp(mh - mh) = 1 exactly
            s += 1.0f;
            uint4 hv = *(const uint4*)(h + (size_t)node * CH + c8);
            acc[0] += bflo(hv.x);
            acc[1] += bfhi(hv.x);
            acc[2] += bflo(hv.y);
            acc[3] += bfhi(hv.y);
            acc[4] += bflo(hv.z);
            acc[5] += bfhi(hv.z);
            acc[6] += bflo(hv.w);
            acc[7] += bfhi(hv.w);
        }
#pragma unroll
        for (int o = 16; o < 64; o <<= 1) {
            s += __shfl_xor(s, o, 64);
#pragma unroll
            for (int k = 0; k < 8; ++k) acc[k] += __shfl_xor(acc[k], o, 64);
        }
        if (g == 0) {
            const float inv = 1.f / (s + 1e-16f);
            float o0[8];
#pragma unroll
            for (int k = 0; k < 8; ++k) {
                float v = acc[k] * inv + bias[c8 + k];
                o0[k] = v > 0.f ? v : __expf(v) - 1.f;   // ELU alpha=1
            }
            float4 lo = make_float4(o0[0], o0[1], o0[2], o0[3]);
            float4 hi = make_float4(o0[4], o0[5], o0[6], o0[7]);
            *(float4*)(out + (size_t)node * CH + c8) = lo;
            *(float4*)(out + (size_t)node * CH + c8 + 4) = hi;
        }
    }
}

extern "C" void kernel_launch(void* const* d_in, const int* in_sizes, int n_in,
                              void* d_out, int out_size, void* d_ws, size_t ws_size,
                              hipStream_t stream)
{
    const float* x       = (const float*)d_in[0];
    const int*   ei      = (const int*)d_in[1];
    const float* W       = (const float*)d_in[2];
    const float* att_src = (const float*)d_in[3];
    const float* att_dst = (const float*)d_in[4];
    const float* bias    = (const float*)d_in[5];
    float* out = (float*)d_out;
    const int N = in_sizes[0] / CH;
    const int E = in_sizes[1] / 2;
    const int NB = (N + NPB - 1) / NPB;   // coarse buckets (391 for N=50000)

    char* p = (char*)d_ws;
    auto alloc = [&](size_t bytes) { char* r = p; p += (bytes + 255) & ~(size_t)255; return r; };
    u16*   h    = (u16*)alloc((size_t)N * CH * 2);             // 12.8 MB
    float* asrc = (float*)alloc((size_t)N * NHEAD * 4);        // 0.8 MB
    float* adst = (float*)alloc((size_t)N * NHEAD * 4);        // 0.8 MB
    int*   gcur = (int*)alloc((size_t)NB * GPAD * 4);          // 25 KB
    u32*   rec  = (u32*)alloc((size_t)NB * BCAP * 4);          // 9.6 MB
    u32*   Wg   = (u32*)alloc((size_t)CH * CH / 2 * 4);        // 32 KB bf16 W

    const int gemmBlocks = (N + ROWS_PER_BLOCK - 1) / ROWS_PER_BLOCK;
    init_kernel<<<16, 256, 0, stream>>>(W, Wg, gcur, NB * GPAD);
    gemmbin_kernel<<<BINA_BLOCKS + gemmBlocks, 256, 0, stream>>>(
        x, Wg, att_src, att_dst, h, asrc, adst, N, ei, gcur, rec, E, NB);
    binBagg_kernel<<<2 * NB, 512, 0, stream>>>(h, asrc, adst, gcur, rec, bias, out, N);
}

// Round 10
// 197.338 us; speedup vs baseline: 1.0965x; 1.0965x over previous
//
#include <hip/hip_runtime.h>

typedef unsigned short u16;
typedef unsigned int u32;

#define CH 128      // IN_CH == HEADS*HEAD_DIM == 128
#define NHEAD 4
#define NEG_SLOPE 0.2f
#define ROWS_PER_BLOCK 32   // x-tile rows per block
#define XPAD 132            // xs row stride (fp32): breaks 16-way column-read conflicts

#define LOG_NPB 7
#define NPB 128             // nodes per coarse bucket (bucket = dst >> 7)
#define NBMAX 400           // LDS bound on bucket count (N <= 51200)
#define BCAP 6144           // records per bucket (E[edges]=4096, ~32 sigma)
#define KMB 6               // BCAP / 1024 records per thread in binBagg
#define GPAD 16             // bucket-cursor padding (one per 64B line)
#define BINA_BLOCKS 256     // global atomics = BINA_BLOCKS * NB ~ 100k

typedef __attribute__((ext_vector_type(8))) short bf16x8;   // 8 bf16 (4 VGPRs)
typedef __attribute__((ext_vector_type(4))) float f32x4;    // MFMA C/D

static __device__ __forceinline__ float bitf(u32 i) {
    float f; __builtin_memcpy(&f, &i, 4); return f;
}
static __device__ __forceinline__ float bflo(u32 v) { return bitf(v << 16); }
static __device__ __forceinline__ float bfhi(u32 v) { return bitf(v & 0xffff0000u); }
static __device__ __forceinline__ u16 f2bf(float f) {
    u32 i; __builtin_memcpy(&i, &f, 4);
    return (u16)((i + 0x7fffu + ((i >> 16) & 1u)) >> 16);   // RNE
}
static __device__ __forceinline__ float lrelu(float v) { return v > 0.f ? v : NEG_SLOPE * v; }

// edge_index accessor: mode32 ? int32 layout : int64 layout (low word)
static __device__ __forceinline__ int ei_at(const int* __restrict__ ei, int mode32, size_t idx) {
    return mode32 ? ei[idx] : ei[2 * idx];
}

// ---------------- k0: init — zero gcur + build SWIZZLED bf16 W fragments ----------------
// Wsw[(nt*4+ks)*64 + lane] (uint4 = 8 bf16) holds the B-fragment for
// mfma_f32_16x16x32_bf16: elem j <-> W[ks*32 + (lane>>4)*4 + (j&3) + 16*(j>>2)]
//                                    [nt*16 + (lane&15)]
// so the K-loop's B-load is ONE conflict-free lane-linear ds_read_b128.
__global__ __launch_bounds__(256) void init_kernel(
    const float* __restrict__ W, uint4* __restrict__ Wsw, int* __restrict__ gcur, int nGcur)
{
    const int t = blockIdx.x * 256 + threadIdx.x;    // grid 16x256 = 4096
    if (t < 2048) {
        const int lane = t & 63, ks = (t >> 6) & 3, nt = t >> 8;
        const int col = nt * 16 + (lane & 15);
        const int kb = ks * 32 + ((lane >> 4) << 2);
        u16 v[8];
#pragma unroll
        for (int j = 0; j < 8; ++j) {
            int kk = kb + (j & 3) + ((j >> 2) << 4);
            v[j] = f2bf(W[(size_t)kk * CH + col]);
        }
        uint4 q;
        q.x = (u32)v[0] | ((u32)v[1] << 16);
        q.y = (u32)v[2] | ((u32)v[3] << 16);
        q.z = (u32)v[4] | ((u32)v[5] << 16);
        q.w = (u32)v[6] | ((u32)v[7] << 16);
        Wsw[t] = q;
    }
    for (int i = t; i < nGcur; i += 4096) gcur[i] = 0;
}

// ======== k1: blocks [0,BINA_BLOCKS) do binA, rest do MFMA GEMM ========
// GEMM h = x@W + logits via double-bf16 MFMA: x = x_hi + x_lo (split residual
// ~2^-17 relative -> same accuracy class as fp32 x fmaf with bf16 W).
// Wave w: rows rt*16..+15 (rt=w&1), cols (w>>1)*64..+63 (4 n-tiles).
// Logits from fp32 accumulators (each wave owns complete (row, head) pairs).
__global__ __launch_bounds__(256) void gemmbin_kernel(
    const float* __restrict__ x, const uint4* __restrict__ Wsw,
    const float* __restrict__ att_src, const float* __restrict__ att_dst,
    u16* __restrict__ h, float* __restrict__ asrc, float* __restrict__ adst, int N,
    const int* __restrict__ ei, int* __restrict__ gcur, u32* __restrict__ rec,
    int E, int NB)
{
    __shared__ float xs[ROWS_PER_BLOCK][XPAD];   // 16.9 KB (overlaid: binA hist / h-tile)
    __shared__ uint4 Wb[2048];                   // 32 KB swizzled bf16 W fragments

    const int tid = threadIdx.x;

    if (blockIdx.x < BINA_BLOCKS) {
        // ---- binA: partition edges into coarse buckets ----
        int* hist  = (int*)&xs[0][0];          // 3 * NBMAX ints = 4.8 KB <= 16.9 KB
        int* hbase = hist + NBMAX;
        int* hcur  = hbase + NBMAX;
        const int mode32 = __syncthreads_or(ei[2 * tid + 1] != 0);
        for (int b = tid; b < NB; b += 256) { hist[b] = 0; hcur[b] = 0; }
        __syncthreads();
        const int chunk = (E + BINA_BLOCKS - 1) / BINA_BLOCKS;
        const int beg0 = blockIdx.x * chunk;
        const int end0 = min(E, beg0 + chunk);
#pragma unroll 4
        for (int e = beg0 + tid; e < end0; e += 256) {
            int dj = ei_at(ei, mode32, (size_t)E + e);
            atomicAdd(&hist[dj >> LOG_NPB], 1);
        }
        __syncthreads();
        for (int b = tid; b < NB; b += 256) {
            int c = hist[b];
            hbase[b] = c ? atomicAdd(&gcur[b * GPAD], c) : 0;
        }
        __syncthreads();
#pragma unroll 4
        for (int e = beg0 + tid; e < end0; e += 256) {
            int dj = ei_at(ei, mode32, (size_t)E + e);
            int sj = ei_at(ei, mode32, (size_t)e);
            int bkt = dj >> LOG_NPB;
            int r = atomicAdd(&hcur[bkt], 1);
            int pos = hbase[bkt] + r;
            if (pos < BCAP)
                rec[(size_t)bkt * BCAP + pos] = ((u32)sj << LOG_NPB) | (u32)(dj & (NPB - 1));
        }
        return;
    }

    // ---- stage ----
    const int gb = blockIdx.x - BINA_BLOCKS;
    const int r0b = gb * ROWS_PER_BLOCK;
#pragma unroll
    for (int i = 0; i < 8; ++i) Wb[tid + i * 256] = Wsw[tid + i * 256];
#pragma unroll
    for (int i = 0; i < 4; ++i) {
        int f = tid + i * 256;
        int row = f >> 5;
        int col = (f & 31) * 4;
        if (r0b + row < N)
            *(float4*)&xs[row][col] = *(const float4*)(x + (size_t)(r0b + row) * CH + col);
    }
    __syncthreads();

    const int lane = tid & 63;
    const int w = tid >> 6;
    const int g = lane >> 4;          // k-group
    const int a15 = lane & 15;
    const int rt = w & 1;             // row tile
    const int cb4 = w >> 1;           // col base / 64

    f32x4 acc[4] = {};                // acc[ct]: D[rt*16 + 4g+i][cb4*64 + ct*16 + a15]

#pragma unroll
    for (int ks = 0; ks < 4; ++ks) {
        const float* xr = &xs[rt * 16 + a15][ks * 32 + g * 4];
        float4 av0 = *(const float4*)xr;          // k = ks*32 + 4g + 0..3
        float4 av1 = *(const float4*)(xr + 16);   // k = ks*32 + 16 + 4g + 0..3
        float av[8] = {av0.x, av0.y, av0.z, av0.w, av1.x, av1.y, av1.z, av1.w};
        bf16x8 ahi, alo;
#pragma unroll
        for (int j = 0; j < 8; ++j) {
            u16 hb = f2bf(av[j]);
            ahi[j] = (short)hb;
            alo[j] = (short)f2bf(av[j] - bflo(hb));
        }
#pragma unroll
        for (int ct = 0; ct < 4; ++ct) {
            bf16x8 b = *(const bf16x8*)&Wb[((cb4 * 4 + ct) * 4 + ks) * 64 + lane];
            acc[ct] = __builtin_amdgcn_mfma_f32_16x16x32_bf16(alo, b, acc[ct], 0, 0, 0);
            acc[ct] = __builtin_amdgcn_mfma_f32_16x16x32_bf16(ahi, b, acc[ct], 0, 0, 0);
        }
    }

    // ---- logits from fp32 acc: head hb0 = 2*cb4 (ct 0,1), hb0+1 (ct 2,3) ----
    float as_c[4], ad_c[4];
#pragma unroll
    for (int ct = 0; ct < 4; ++ct) {
        int c = cb4 * 64 + ct * 16 + a15;
        as_c[ct] = att_src[c];
        ad_c[ct] = att_dst[c];
    }
#pragma unroll
    for (int i = 0; i < 4; ++i) {
        float s0 = acc[0][i] * as_c[0] + acc[1][i] * as_c[1];
        float s1 = acc[2][i] * as_c[2] + acc[3][i] * as_c[3];
        float d0 = acc[0][i] * ad_c[0] + acc[1][i] * ad_c[1];
        float d1 = acc[2][i] * ad_c[2] + acc[3][i] * ad_c[3];
#pragma unroll
        for (int o = 1; o < 16; o <<= 1) {      // reduce over a15 (16-lane groups)
            s0 += __shfl_xor(s0, o, 64);
            s1 += __shfl_xor(s1, o, 64);
            d0 += __shfl_xor(d0, o, 64);
            d1 += __shfl_xor(d1, o, 64);
        }
        if (a15 == 0) {
            int row = r0b + rt * 16 + g * 4 + i;
            if (row < N) {
                int hb0 = cb4 * 2;
                asrc[row * NHEAD + hb0]     = s0;
                asrc[row * NHEAD + hb0 + 1] = s1;
                adst[row * NHEAD + hb0]     = d0;
                adst[row * NHEAD + hb0 + 1] = d1;
            }
        }
    }

    // ---- h store: D -> LDS bf16 tile (overlay xs) -> coalesced u32 global ----
    __syncthreads();                   // all waves done reading xs
    u16* ht = (u16*)&xs[0][0];         // [32][128] bf16 tile, 8 KB
#pragma unroll
    for (int ct = 0; ct < 4; ++ct)
#pragma unroll
        for (int i = 0; i < 4; ++i)
            ht[(rt * 16 + g * 4 + i) * CH + cb4 * 64 + ct * 16 + a15] = f2bf(acc[ct][i]);
    __syncthreads();
    {
        const u32* ht32 = (const u32*)&xs[0][0];
        const int rw = w * 8;
#pragma unroll
        for (int r = 0; r < 8; ++r) {
            int row = r0b + rw + r;
            if (row < N)
                *(u32*)(h + (size_t)row * CH + lane * 2) = ht32[(rw + r) * 64 + lane];
        }
    }
}

// ======== k2: fused binB + aggregate — one block per bucket, 1024 threads (r8-proven) ====
__global__ __launch_bounds__(1024) void binBagg_kernel(
    const u16* __restrict__ h, const float* __restrict__ asrc, const float* __restrict__ adst,
    const int* __restrict__ gcur, const u32* __restrict__ rec,
    const float* __restrict__ bias, float* __restrict__ out, int N)
{
    __shared__ int outb[BCAP + 32];   // 24.7 KB (+pad for prefetch overread)
    __shared__ int lcnt[NPB];
    __shared__ int lsc[NPB];
    __shared__ int lcur[NPB];
    const int tid = threadIdx.x;
    const int bkt = blockIdx.x;
    int cnt0 = gcur[bkt * GPAD];
    cnt0 = cnt0 < BCAP ? cnt0 : BCAP;
    const size_t rbase = (size_t)bkt * BCAP;

    if (tid < NPB) { lcnt[tid] = 0; lcur[tid] = 0; }

    u32 rc[KMB];
#pragma unroll
    for (int k = 0; k < KMB; ++k) {
        int i = tid + k * 1024;
        rc[k] = (i < cnt0) ? rec[rbase + i] : 0xffffffffu;   // sj<<7|d < 6.5M, sentinel safe
    }
    __syncthreads();
#pragma unroll
    for (int k = 0; k < KMB; ++k)
        if (rc[k] != 0xffffffffu) atomicAdd(&lcnt[rc[k] & (NPB - 1)], 1);
    __syncthreads();
    if (tid < NPB) lsc[tid] = lcnt[tid];
    __syncthreads();
    for (int o = 1; o < NPB; o <<= 1) {
        int v = (tid < NPB && tid >= o) ? lsc[tid - o] : 0;
        __syncthreads();
        if (tid < NPB) lsc[tid] += v;
        __syncthreads();
    }
#pragma unroll
    for (int k = 0; k < KMB; ++k) {
        if (rc[k] != 0xffffffffu) {
            int local = rc[k] & (NPB - 1);
            int r = atomicAdd(&lcur[local], 1);
            int slot = (lsc[local] - lcnt[local]) + r;
            outb[slot] = (int)(rc[k] >> LOG_NPB);
        }
    }
    __syncthreads();

    // ---- agg phase: wave w handles locals w*8 .. w*8+7 (no barriers below) ----
    const int lane = tid & 63;
    const int wave = tid >> 6;        // 0..15
    const int g = lane >> 4;
    const int l = lane & 15;
    const int c8 = l * 8;
    const int head = l >> 2;

    for (int nl = 0; nl < 8; ++nl) {
        const int local = wave * 8 + nl;
        const int node = (bkt << LOG_NPB) + local;
        if (node >= N) continue;
        const int beg = lsc[local] - lcnt[local];
        const int end = lsc[local];
        const float4 ad4 = *(const float4*)(adst + node * 4);
        const float adh = (head == 0) ? ad4.x : (head == 1) ? ad4.y : (head == 2) ? ad4.z : ad4.w;
        const float4 asl = *(const float4*)(asrc + node * 4);
        const float aslh = (head == 0) ? asl.x : (head == 1) ? asl.y : (head == 2) ? asl.z : asl.w;
        const float mh = lrelu(aslh + adh);   // self-loop logit as softmax shift

        float acc[8];
#pragma unroll
        for (int k = 0; k < 8; ++k) acc[k] = 0.f;
        float s = 0.f;

        int e = beg + g;
        if (e < end) {
            uint4 hC[4]; float aC[4];
#pragma unroll
            for (int i = 0; i < 4; ++i) {              // prologue batch: e+0,4,8,12
                int ei = e + 4 * i;
                int j = outb[ei];                      // LDS, padded-safe
                j = ((u32)j < (u32)N) ? j : 0;
                float a = asrc[j * NHEAD + head];
                aC[i] = (ei < end) ? a : -1e30f;
                hC[i] = *(const uint4*)(h + (size_t)j * CH + c8);
            }
            for (;;) {
                const int ebase = e + 16;
                uint4 hP[4]; float aP[4];
#pragma unroll
                for (int i = 0; i < 4; ++i) {          // prefetch next batch
                    int ei = ebase + 4 * i;
                    int j = outb[ei];
                    j = ((u32)j < (u32)N) ? j : 0;
                    float a = asrc[j * NHEAD + head];
                    aP[i] = (ei < end) ? a : -1e30f;
                    hP[i] = *(const uint4*)(h + (size_t)j * CH + c8);
                }
#pragma unroll
                for (int i = 0; i < 4; ++i) {          // compute current batch
                    float w = __expf(lrelu(aC[i] + adh) - mh);   // a=-1e30 -> w=0
                    s += w;
                    acc[0] = fmaf(w, bflo(hC[i].x), acc[0]);
                    acc[1] = fmaf(w, bfhi(hC[i].x), acc[1]);
                    acc[2] = fmaf(w, bflo(hC[i].y), acc[2]);
                    acc[3] = fmaf(w, bfhi(hC[i].y), acc[3]);
                    acc[4] = fmaf(w, bflo(hC[i].z), acc[4]);
                    acc[5] = fmaf(w, bfhi(hC[i].z), acc[5]);
                    acc[6] = fmaf(w, bflo(hC[i].w), acc[6]);
                    acc[7] = fmaf(w, bfhi(hC[i].w), acc[7]);
                }
#pragma unroll
                for (int i = 0; i < 4; ++i) { aC[i] = aP[i]; hC[i] = hP[i]; }
                e = ebase;
                if (e >= end) break;
            }
        }
        if (g == 0) {   // self-loop message: w = exp(mh - mh) = 1 exactly
            s += 1.0f;
            uint4 hv = *(const uint4*)(h + (size_t)node * CH + c8);
            acc[0] += bflo(hv.x);
            acc[1] += bfhi(hv.x);
            acc[2] += bflo(hv.y);
            acc[3] += bfhi(hv.y);
            acc[4] += bflo(hv.z);
            acc[5] += bfhi(hv.z);
            acc[6] += bflo(hv.w);
            acc[7] += bfhi(hv.w);
        }
#pragma unroll
        for (int o = 16; o < 64; o <<= 1) {
            s += __shfl_xor(s, o, 64);
#pragma unroll
            for (int k = 0; k < 8; ++k) acc[k] += __shfl_xor(acc[k], o, 64);
        }
        if (g == 0) {
            const float inv = 1.f / (s + 1e-16f);
            float o0[8];
#pragma unroll
            for (int k = 0; k < 8; ++k) {
                float v = acc[k] * inv + bias[c8 + k];
                o0[k] = v > 0.f ? v : __expf(v) - 1.f;   // ELU alpha=1
            }
            float4 lo = make_float4(o0[0], o0[1], o0[2], o0[3]);
            float4 hi = make_float4(o0[4], o0[5], o0[6], o0[7]);
            *(float4*)(out + (size_t)node * CH + c8) = lo;
            *(float4*)(out + (size_t)node * CH + c8 + 4) = hi;
        }
    }
}

extern "C" void kernel_launch(void* const* d_in, const int* in_sizes, int n_in,
                              void* d_out, int out_size, void* d_ws, size_t ws_size,
                              hipStream_t stream)
{
    const float* x       = (const float*)d_in[0];
    const int*   ei      = (const int*)d_in[1];
    const float* W       = (const float*)d_in[2];
    const float* att_src = (const float*)d_in[3];
    const float* att_dst = (const float*)d_in[4];
    const float* bias    = (const float*)d_in[5];
    float* out = (float*)d_out;
    const int N = in_sizes[0] / CH;
    const int E = in_sizes[1] / 2;
    const int NB = (N + NPB - 1) / NPB;   // coarse buckets (391 for N=50000)

    char* p = (char*)d_ws;
    auto alloc = [&](size_t bytes) { char* r = p; p += (bytes + 255) & ~(size_t)255; return r; };
    u16*   h    = (u16*)alloc((size_t)N * CH * 2);             // 12.8 MB
    float* asrc = (float*)alloc((size_t)N * NHEAD * 4);        // 0.8 MB
    float* adst = (float*)alloc((size_t)N * NHEAD * 4);        // 0.8 MB
    int*   gcur = (int*)alloc((size_t)NB * GPAD * 4);          // 25 KB
    u32*   rec  = (u32*)alloc((size_t)NB * BCAP * 4);          // 9.6 MB
    uint4* Wsw  = (uint4*)alloc((size_t)2048 * 16);            // 32 KB swizzled bf16 W

    const int gemmBlocks = (N + ROWS_PER_BLOCK - 1) / ROWS_PER_BLOCK;
    init_kernel<<<16, 256, 0, stream>>>(W, Wsw, gcur, NB * GPAD);
    gemmbin_kernel<<<BINA_BLOCKS + gemmBlocks, 256, 0, stream>>>(
        x, Wsw, att_src, att_dst, h, asrc, adst, N, ei, gcur, rec, E, NB);
    binBagg_kernel<<<NB, 1024, 0, stream>>>(h, asrc, adst, gcur, rec, bias, out, N);
}